// Round 3
// baseline (464.113 us; speedup 1.0000x reference)
//
#include <hip/hip_runtime.h>
#include <cstdint>
#include <cstddef>

// Problem constants (from reference setup_inputs)
constexpr int P  = 200000;   // points
constexpr int C  = 256;      // clicks
constexpr int NC = 200;      // classes
#define DICE_TH 0.4f
#define CLS_TH  0.5f
#define LN_EPS  1e-5f

// gram split-K config: KC * NCHUNK == P, KC % 32 == 0
constexpr int KC = 800;
constexpr int NCHUNK = 250;
constexpr int NSTEP = KC / 32;

// workspace byte offsets (total < 700 KB)
constexpr size_t WS_G       = 0;        // 256*256*4 = 262144
constexpr size_t WS_S       = 262144;   // 256*4
constexpr size_t WS_PROW    = 263168;   // 256*200*4 = 204800
constexpr size_t WS_PT      = 467968;   // 200*256*4 = 204800
constexpr size_t WS_COND    = 672768;   // 256*4*8 = 8192
constexpr size_t WS_MSTART  = 680960;   // 257*4
constexpr size_t WS_MEMBERS = 682240;   // 256*4

typedef float floatx16 __attribute__((ext_vector_type(16)));
typedef __bf16 bf16x8 __attribute__((ext_vector_type(8)));
typedef unsigned short ushort8 __attribute__((ext_vector_type(8)));

__device__ __forceinline__ unsigned short f2bf(float f) {
  unsigned u = __builtin_bit_cast(unsigned, f);
  unsigned r = u + 0x7FFFu + ((u >> 16) & 1u);   // RNE
  return (unsigned short)(r >> 16);
}

// ---------------------------------------------------------------------------
// Kernel 1: G = M^T M via bf16 MFMA (fp32 accumulate), split-K atomicAdd.
// Symmetric: only tiles (0,0),(0,1),(1,1) computed; cond reads mirror for
// the (1,0) quadrant. Column sums s fused into diag-block staging (fp32).
// LDS layout: [col][k] bf16, row stride 40 (32+8 pad -> conflict-free b128).
// v2: register prefetch of next k-step overlapped with MFMA; 2x finer split-K.
// ---------------------------------------------------------------------------
constexpr int LDA = 40;

__global__ __launch_bounds__(256, 2) void gram_mfma_kernel(
    const float* __restrict__ M, float* __restrict__ G, float* __restrict__ s) {
  __shared__ unsigned short Abf[128 * LDA];
  __shared__ unsigned short Bbf[128 * LDA];

  const int type = blockIdx.x;              // 0:(0,0) 1:(0,128) 2:(128,128)
  const int i0 = (type == 2) ? 128 : 0;
  const int j0 = (type == 0) ? 0 : 128;
  const bool diag = (type != 1);
  const int tid = threadIdx.x;
  const int wv = tid >> 6, lane = tid & 63;
  const int c = tid & 127, h = tid >> 7;    // staging: column, k-half (16 ks)
  const int k0 = blockIdx.y * KC;

  floatx16 acc[4];
#pragma unroll
  for (int t = 0; t < 4; ++t)
#pragma unroll
    for (int r = 0; r < 16; ++r) acc[t][r] = 0.f;
  float ssum = 0.f;

  const int mrow = lane & 31;
  const int kgrp = (lane >> 5) * 8;

  float va[16], vb[16];
  {
    const float* colA = M + (size_t)(k0 + h * 16) * 256 + i0 + c;
#pragma unroll
    for (int u = 0; u < 16; ++u) va[u] = colA[(size_t)u * 256];
    if (!diag) {
      const float* colB = M + (size_t)(k0 + h * 16) * 256 + j0 + c;
#pragma unroll
      for (int u = 0; u < 16; ++u) vb[u] = colB[(size_t)u * 256];
    }
  }

  for (int step = 0; step < NSTEP; ++step) {
    // convert current regs -> LDS (+ column-sum on diag)
    {
      if (diag) {
#pragma unroll
        for (int u = 0; u < 16; ++u) ssum += va[u];
      }
      ushort8 lo, hi;
#pragma unroll
      for (int u = 0; u < 8; ++u) { lo[u] = f2bf(va[u]); hi[u] = f2bf(va[u + 8]); }
      *reinterpret_cast<ushort8*>(&Abf[c * LDA + h * 16]) = lo;
      *reinterpret_cast<ushort8*>(&Abf[c * LDA + h * 16 + 8]) = hi;
      if (!diag) {
#pragma unroll
        for (int u = 0; u < 8; ++u) { lo[u] = f2bf(vb[u]); hi[u] = f2bf(vb[u + 8]); }
        *reinterpret_cast<ushort8*>(&Bbf[c * LDA + h * 16]) = lo;
        *reinterpret_cast<ushort8*>(&Bbf[c * LDA + h * 16 + 8]) = hi;
      }
    }
    __syncthreads();

    // prefetch next step while MFMAs run (waitcnt lands at next convert)
    if (step + 1 < NSTEP) {
      const int kb = k0 + (step + 1) * 32 + h * 16;
      const float* colA = M + (size_t)kb * 256 + i0 + c;
#pragma unroll
      for (int u = 0; u < 16; ++u) va[u] = colA[(size_t)u * 256];
      if (!diag) {
        const float* colB = M + (size_t)kb * 256 + j0 + c;
#pragma unroll
        for (int u = 0; u < 16; ++u) vb[u] = colB[(size_t)u * 256];
      }
    }

    const unsigned short* Bsrc = diag ? Abf : Bbf;
#pragma unroll
    for (int sub = 0; sub < 2; ++sub) {
      const int ko = sub * 16 + kgrp;
      bf16x8 a = __builtin_bit_cast(
          bf16x8, *reinterpret_cast<const ushort8*>(
                      &Abf[(32 * wv + mrow) * LDA + ko]));
#pragma unroll
      for (int t = 0; t < 4; ++t) {
        bf16x8 b = __builtin_bit_cast(
            bf16x8, *reinterpret_cast<const ushort8*>(
                        &Bsrc[(32 * t + mrow) * LDA + ko]));
        acc[t] = __builtin_amdgcn_mfma_f32_32x32x16_bf16(a, b, acc[t], 0, 0, 0);
      }
    }
    __syncthreads();
  }

  // epilogue: C/D layout col=lane&31, row=(r&3)+8*(r>>2)+4*(lane>>5)
#pragma unroll
  for (int t = 0; t < 4; ++t) {
    const int gc = j0 + 32 * t + (lane & 31);
#pragma unroll
    for (int r = 0; r < 16; ++r) {
      const int gr = i0 + 32 * wv + (r & 3) + 8 * (r >> 2) + 4 * (lane >> 5);
      atomicAdd(&G[(size_t)gr * 256 + gc], acc[t][r]);
    }
  }
  if (diag) atomicAdd(&s[i0 + c], ssum);
}

// ---------------------------------------------------------------------------
// Kernel 2: layernorm of cls_logits -> p (row-major) and pT (transposed)
// ---------------------------------------------------------------------------
__global__ __launch_bounds__(64) void ln_kernel(const float* __restrict__ cls,
                                                float* __restrict__ p_row,
                                                float* __restrict__ pT) {
  const int c = blockIdx.x;
  const int t = threadIdx.x;
  const float* x = cls + (size_t)c * NC;
  float v0 = x[t];
  float v1 = x[t + 64];
  float v2 = (t < 72) ? x[t + 128] : 0.f;

  float sum = v0 + v1 + v2;
#pragma unroll
  for (int o = 32; o > 0; o >>= 1) sum += __shfl_xor(sum, o);
  const float mu = sum / (float)NC;

  float d0 = v0 - mu, d1 = v1 - mu, d2 = (t < 72) ? (v2 - mu) : 0.f;
  float sq = d0 * d0 + d1 * d1 + d2 * d2;
#pragma unroll
  for (int o = 32; o > 0; o >>= 1) sq += __shfl_xor(sq, o);
  const float var = sq / (float)NC;
  const float inv = 1.0f / sqrtf(var + LN_EPS);

  float p0 = d0 * inv, p1 = d1 * inv, p2 = d2 * inv;
  p_row[(size_t)c * NC + t] = p0;
  p_row[(size_t)c * NC + t + 64] = p1;
  pT[(size_t)t * C + c] = p0;
  pT[(size_t)(t + 64) * C + c] = p1;
  if (t < 72) {
    p_row[(size_t)c * NC + t + 128] = p2;
    pT[(size_t)(t + 128) * C + c] = p2;
  }
}

// ---------------------------------------------------------------------------
// Kernel 3: cond[i][j] = (dice > 0.4) && (sim > 0.5), packed 4x u64 per row.
// G's (i>=128, j<128) quadrant was not written (symmetry) -> read mirror.
// v2: 4 independent FMA chains for ILP.
// ---------------------------------------------------------------------------
__global__ __launch_bounds__(256) void cond_kernel(
    const float* __restrict__ G, const float* __restrict__ s,
    const float* __restrict__ p_row, const float* __restrict__ pT,
    unsigned long long* __restrict__ condW) {
  __shared__ float pi[NC];
  const int i = blockIdx.x;
  const int j = threadIdx.x;
  if (j < NC) pi[j] = p_row[(size_t)i * NC + j];
  __syncthreads();

  const float si = s[i];
  const float sj = s[j];
  const float g = (i >= 128 && j < 128) ? G[(size_t)j * C + i]
                                        : G[(size_t)i * C + j];
  const float dice = 2.f * g / (si + sj);

  float a0 = 0.f, a1 = 0.f, a2 = 0.f, a3 = 0.f;
#pragma unroll 2
  for (int k = 0; k < NC; k += 4) {
    a0 = fmaf(pi[k + 0], pT[(size_t)(k + 0) * C + j], a0);
    a1 = fmaf(pi[k + 1], pT[(size_t)(k + 1) * C + j], a1);
    a2 = fmaf(pi[k + 2], pT[(size_t)(k + 2) * C + j], a2);
    a3 = fmaf(pi[k + 3], pT[(size_t)(k + 3) * C + j], a3);
  }
  const float acc = (a0 + a1) + (a2 + a3);

  const bool cnd = (dice > DICE_TH) && (acc > CLS_TH);
  unsigned long long m = __ballot(cnd);
  if ((j & 63) == 0) condW[i * 4 + (j >> 6)] = m;
}

// ---------------------------------------------------------------------------
// Kernel 4: sequential greedy scan (exact reference semantics), single wave.
// v2: software-pipelined row prefetch in the leader loop.
// ---------------------------------------------------------------------------
__global__ __launch_bounds__(64) void scan_kernel(
    const unsigned long long* __restrict__ condW,
    float* __restrict__ out_labels, float* __restrict__ out_valid,
    int* __restrict__ mstart, int* __restrict__ members) {
  __shared__ unsigned long long cS[C * 4];
  __shared__ int cnt[C];
  __shared__ int ms[C + 1];
  const int t = threadIdx.x;

  for (int idx = t; idx < C * 4; idx += 64) cS[idx] = condW[idx];
  for (int idx = t; idx < C; idx += 64) cnt[idx] = 0;
  __syncthreads();

  unsigned long long asg[4] = {0ull, 0ull, 0ull, 0ull};
  int lab[4] = {-1, -1, -1, -1};   // lab[w] is label of column w*64 + t

  unsigned long long r0 = cS[0], r1 = cS[1], r2 = cS[2], r3 = cS[3];
  for (int i = 0; i < C; ++i) {
    const int nx = (i + 1 < C) ? (i + 1) * 4 : 0;
    unsigned long long n0 = cS[nx], n1 = cS[nx + 1], n2 = cS[nx + 2],
                       n3 = cS[nx + 3];
    const int w = i >> 6, b = i & 63;
    if (!((asg[w] >> b) & 1ull)) {   // leader i: take unassigned matches
      unsigned long long tk;
      tk = r0 & ~asg[0]; asg[0] |= tk; if ((tk >> t) & 1ull) lab[0] = i;
      tk = r1 & ~asg[1]; asg[1] |= tk; if ((tk >> t) & 1ull) lab[1] = i;
      tk = r2 & ~asg[2]; asg[2] |= tk; if ((tk >> t) & 1ull) lab[2] = i;
      tk = r3 & ~asg[3]; asg[3] |= tk; if ((tk >> t) & 1ull) lab[3] = i;
    }
    r0 = n0; r1 = n1; r2 = n2; r3 = n3;
  }

  // counts per leader
#pragma unroll
  for (int w = 0; w < 4; ++w)
    if (lab[w] >= 0) atomicAdd(&cnt[lab[w]], 1);
  __syncthreads();

  if (t == 0) {
    ms[0] = 0;
    for (int c2 = 0; c2 < C; ++c2) ms[c2 + 1] = ms[c2] + cnt[c2];
  }
  __syncthreads();
  for (int idx = t; idx < C; idx += 64) cnt[idx] = ms[idx];
  __syncthreads();
#pragma unroll
  for (int w = 0; w < 4; ++w) {
    if (lab[w] >= 0) {
      int pos = atomicAdd(&cnt[lab[w]], 1);
      members[pos] = w * 64 + t;
    }
  }
#pragma unroll
  for (int w = 0; w < 4; ++w) {
    const int col = w * 64 + t;
    out_labels[col] = (float)lab[w];
    out_valid[col] = (ms[col + 1] > ms[col]) ? 1.0f : 0.0f;
  }
  for (int idx = t; idx < C + 1; idx += 64) mstart[idx] = ms[idx];
}

// ---------------------------------------------------------------------------
// Kernel 5: new_masks[p][c] = valid(c) ? max over members of M[p][j] : 0
// v2: 16 rows per block (fewer blocks, fewer mstart/members reloads)
// ---------------------------------------------------------------------------
__global__ __launch_bounds__(256) void merge_masks_kernel(
    const float* __restrict__ M, const int* __restrict__ mstart,
    const int* __restrict__ members, float* __restrict__ out_masks) {
  __shared__ float rows[16 * 256];
  __shared__ int msS[C + 1];
  __shared__ int memS[C];
  const int tid = threadIdx.x;
  const size_t p0 = (size_t)blockIdx.x * 16;

  msS[tid] = mstart[tid];
  if (tid == 0) msS[C] = mstart[C];
  memS[tid] = members[tid];

  const float4* src = reinterpret_cast<const float4*>(M + p0 * 256);
#pragma unroll
  for (int it = 0; it < 4; ++it)
    reinterpret_cast<float4*>(rows)[it * 256 + tid] = src[it * 256 + tid];
  __syncthreads();

  const int st = msS[tid], en = msS[tid + 1];
  float mx[16];
  if (en > st) {
    const int m0 = memS[st];
#pragma unroll
    for (int r = 0; r < 16; ++r) mx[r] = rows[r * 256 + m0];
    for (int k = st + 1; k < en; ++k) {
      const int mm = memS[k];
#pragma unroll
      for (int r = 0; r < 16; ++r) mx[r] = fmaxf(mx[r], rows[r * 256 + mm]);
    }
  } else {
#pragma unroll
    for (int r = 0; r < 16; ++r) mx[r] = 0.f;
  }
#pragma unroll
  for (int r = 0; r < 16; ++r) out_masks[(p0 + r) * 256 + tid] = mx[r];
}

// ---------------------------------------------------------------------------
// Kernel 6: new_cls[c][k] = valid(c) ? max over members of cls[j][k] : 0
// ---------------------------------------------------------------------------
__global__ __launch_bounds__(256) void merge_cls_kernel(
    const float* __restrict__ cls, const int* __restrict__ mstart,
    const int* __restrict__ members, float* __restrict__ out_cls) {
  __shared__ int se[2];
  const int c = blockIdx.x;
  const int t = threadIdx.x;
  if (t < 2) se[t] = mstart[c + t];
  __syncthreads();
  const int st = se[0], en = se[1];
  if (t < NC) {
    float mx = 0.f;
    if (en > st) {
      mx = cls[(size_t)members[st] * NC + t];
      for (int k = st + 1; k < en; ++k)
        mx = fmaxf(mx, cls[(size_t)members[k] * NC + t]);
    }
    out_cls[(size_t)c * NC + t] = mx;
  }
}

// ---------------------------------------------------------------------------
extern "C" void kernel_launch(void* const* d_in, const int* in_sizes, int n_in,
                              void* d_out, int out_size, void* d_ws,
                              size_t ws_size, hipStream_t stream) {
  const float* M = (const float*)d_in[0];    // [P, C] fp32
  const float* cls = (const float*)d_in[1];  // [C, NC] fp32

  float* out = (float*)d_out;
  char* ws = (char*)d_ws;
  float* G = (float*)(ws + WS_G);
  float* s = (float*)(ws + WS_S);
  float* p_row = (float*)(ws + WS_PROW);
  float* pT = (float*)(ws + WS_PT);
  unsigned long long* condW = (unsigned long long*)(ws + WS_COND);
  int* mstart = (int*)(ws + WS_MSTART);
  int* members = (int*)(ws + WS_MEMBERS);

  float* out_labels = out;
  float* out_valid = out + 256;
  float* out_masks = out + 512;
  float* out_cls = out + 512 + (size_t)P * 256;

  // zero accumulators (G and s are contiguous at ws start)
  hipMemsetAsync(ws, 0, WS_S + 1024, stream);

  gram_mfma_kernel<<<dim3(3, NCHUNK), 256, 0, stream>>>(M, G, s);
  ln_kernel<<<C, 64, 0, stream>>>(cls, p_row, pT);
  cond_kernel<<<C, 256, 0, stream>>>(G, s, p_row, pT, condW);
  scan_kernel<<<1, 64, 0, stream>>>(condW, out_labels, out_valid, mstart,
                                    members);
  merge_masks_kernel<<<P / 16, 256, 0, stream>>>(M, mstart, members, out_masks);
  merge_cls_kernel<<<C, 256, 0, stream>>>(cls, mstart, members, out_cls);
}